// Round 14
// baseline (1363.547 us; speedup 1.0000x reference)
//
#include <hip/hip_runtime.h>
#include <hip/hip_bf16.h>
#include <math.h>

// ---------------- problem constants ----------------
#define N_IMG 64
#define CH    64      // PCN_H
#define F1_R  136     // feat1 padded rows: row y stored at y+4  (used 1..133)
#define F1_C  136     // feat1 padded cols: col x stored at x+4  (used 2..133)
// feat1 channel-last: [n][F1_R][F1_C][64] bf16
#define F1_IMG_STRIDE ((size_t)F1_R * F1_C * 64)
#define F1_ROW_STRIDE (F1_C * 64)
#define FEAT1_BYTES ((size_t)N_IMG * F1_IMG_STRIDE * 2)
#define LINPT_BYTES (262144 * 4)
#define W2BF_BYTES (36864 * 2)
// pre2 (CHUNKED): conv2 pre-pool output for 32 images, [32][128][128][64] bf16 = 67108864 B
// d_ws usage: 151519232 + 1048576 + 73728 + 67108864 = 219750400 B (< 256 MiB)

// d_out layout (floats):
//   feature_map (8,64,8,64,64)  : [0, 16777216)
//   counts      (8,1,8,64,64)   : [16777216, 17039360)
//   rgb_map     (8,3,8,64,64)   : [17039360, 17825792)
#define OUT_CNT_BASE 16777216
#define OUT_RGB_BASE 17039360

typedef short bf16x8 __attribute__((ext_vector_type(8)));
typedef float f32x4  __attribute__((ext_vector_type(4)));

// mish(x) = x * tanh(softplus(x)) = x * (t^2+2t)/(t^2+2t+2), t=e^x
__device__ __forceinline__ float fast_mish(float x) {
    float xc = fminf(x, 20.0f);
    float t  = __expf(xc);
    float n  = t * (t + 2.0f);
    float y  = x * n / (n + 2.0f);
    return (x > 20.0f) ? x : y;
}

// float -> bf16 bits, round-to-nearest-even (handles +-inf correctly)
__device__ __forceinline__ unsigned short f2bf(float f) {
    unsigned u = __float_as_uint(f);
    unsigned r = (u + 0x7FFFu + ((u >> 16) & 1u)) >> 16;
    return (unsigned short)r;
}

// ------------- kernel 0: w2 -> bf16 [tap][co][ci] (once, global) -------------
__global__ __launch_bounds__(256) void w2cvt_kernel(
    const float* __restrict__ w2, unsigned short* __restrict__ w2bf)
{
    int i = blockIdx.x * 256 + threadIdx.x;    // 36864 = 9*64*64
    if (i < 36864) {
        int t  = i >> 12;
        int co = (i >> 6) & 63;
        int ci = i & 63;
        w2bf[i] = f2bf(w2[(co * 64 + ci) * 9 + t]);
    }
}

// ------------- kernel 1: per-point binning + rgb/count scatter -------------
__global__ __launch_bounds__(256) void point_kernel(
    const float* __restrict__ rgb,
    const float* __restrict__ sxyz,
    const int*   __restrict__ index,
    float*       __restrict__ out,
    int*         __restrict__ lin_pt)
{
    int p = blockIdx.x * 256 + threadIdx.x;      // 64*64*64 = 262144 points
    int n  = p >> 12;
    int r  = p & 4095;
    int hs = r >> 6;
    int ws = r & 63;

    int row = hs * 4 + 2, col = ws * 4 + 2;
    const float* sx = sxyz + (size_t)n * 3 * 65536;
    float X = sx[row * 256 + col];
    float Y = sx[65536 + row * 256 + col];
    float Z = sx[2 * 65536 + row * 256 + col];

    // replicate JAX op order + trunc-toward-zero int cast
    int hb = (int)(((X + 5.0f) * 64.0f) / 10.0f);
    int wb = (int)(((Y + 5.0f) * 64.0f) / 10.0f);
    int vb = (int)((Z * 8.0f) / 3.0f);
    bool valid = (hb >= 0) & (hb < 64) & (wb >= 0) & (wb < 64) & (vb >= 0) & (vb < 8);

    int b   = index[n];
    int lin = ((b * 8 + vb) * 64 + hb) * 64 + wb;
    lin_pt[p] = valid ? lin : -1;

    if (valid) {
        atomicAdd(out + OUT_CNT_BASE + lin, 1.0f);
        int rem = lin & 32767;
        #pragma unroll
        for (int c = 0; c < 3; c++) {
            const float* rg = rgb + (size_t)(n * 3 + c) * 65536;
            float s = 0.0f;
            #pragma unroll
            for (int i = 0; i < 4; i++)
                #pragma unroll
                for (int j = 0; j < 4; j++)
                    s += rg[(hs * 4 + i) * 256 + (ws * 4 + j)];
            atomicAdd(out + OUT_RGB_BASE + b * 98304 + c * 32768 + rem, s * 0.0625f);
        }
    }
}

// ------------- kernel 2: conv1 via MFMA + mish + maxpool3s2 -> feat1 (channel-last) ----------
__global__ __launch_bounds__(1024) void conv1_mfma_kernel(
    const float* __restrict__ rgb,
    const float* __restrict__ w1,
    __hip_bfloat16* __restrict__ feat1)
{
    int b2 = ((blockIdx.x & 7) << 9) + (blockIdx.x >> 3);   // XCD-chunked swizzle (4096 = 8x512)
    const int n  = b2 >> 6;
    const int pr = b2 & 63;
    const int tid  = threadIdx.x;
    const int lane = tid & 63;
    const int w    = tid >> 6;       // 0..15

    __shared__ __align__(16) char smem[81920];
    unsigned short* wlds = (unsigned short*)smem;
    unsigned short* in_t = (unsigned short*)(smem + 4096);

    // ---- stage weights [co][k], k = ci*9 + ky*3 + kx (k>=27 -> 0)
    for (int i = tid; i < 2048; i += 1024) {
        int co = i >> 5, k = i & 31;
        wlds[i] = (k < 27) ? f2bf(w1[co * 27 + k]) : (unsigned short)0;
    }
    // ---- stage input tile: rows 4pr-3..4pr+5, cols -2..261, bf16; tail 16 zeros
    {
        const float* img = rgb + (size_t)n * 3 * 65536;
        for (int i = tid; i < 7144; i += 1024) {
            unsigned short v = 0;
            if (i < 7128) {
                int ci  = i / 2376;
                int rem = i - ci * 2376;
                int rr  = rem / 264;
                int cc  = rem - rr * 264;
                int gy  = 4 * pr - 3 + rr;
                int gx  = cc - 2;
                if (gy >= 0 && gy < 256 && gx >= 0 && gx < 256)
                    v = f2bf(img[ci * 65536 + gy * 256 + gx]);
            }
            in_t[i] = v;
        }
    }
    __syncthreads();

    // ---- per-lane B gather offsets (bytes) for k = (lane>>4)*8 + j
    int boff[8];
    #pragma unroll
    for (int j = 0; j < 8; j++) {
        int k = ((lane >> 4) << 3) + j;
        if (k < 27) {
            int ci = k / 9, t = k - 9 * ci, ky = t / 3, kx = t - 3 * ky;
            boff[j] = (ci * 2376 + 2 * ky * 264 + 2 * kx + (lane & 15)) * 2;
        } else {
            boff[j] = 7128 * 2;     // zero slot
        }
    }

    // ---- A fragments (weights), k-map identical to B
    bf16x8 a[4];
    #pragma unroll
    for (int mt = 0; mt < 4; mt++)
        a[mt] = *reinterpret_cast<const bf16x8*>(
            wlds + (mt * 16 + (lane & 15)) * 32 + ((lane >> 4) << 3));

    f32x4 acc[5][4];
    #pragma unroll
    for (int tt = 0; tt < 5; tt++)
        #pragma unroll
        for (int mt = 0; mt < 4; mt++)
            acc[tt][mt] = (f32x4){0.f, 0.f, 0.f, 0.f};

    const char* in_b = (const char*)in_t;
    #pragma unroll
    for (int tt = 0; tt < 5; tt++) {
        int t5 = w * 5 + tt;             // 0..79: 5 rows x 16 col-tiles
        int r  = t5 >> 4;
        int x0 = (t5 & 15) << 4;
        int base = (r * 264 + x0) * 2;
        unsigned short e[8];
        #pragma unroll
        for (int j = 0; j < 8; j++)
            e[j] = *reinterpret_cast<const unsigned short*>(in_b + base + boff[j]);
        bf16x8 b;
        #pragma unroll
        for (int j = 0; j < 8; j++) b[j] = (short)e[j];
        #pragma unroll
        for (int mt = 0; mt < 4; mt++)
            acc[tt][mt] = __builtin_amdgcn_mfma_f32_16x16x32_bf16(a[mt], b, acc[tt][mt], 0, 0, 0);
    }

    __syncthreads();   // wlds/in_t dead; reuse LDS as pool tile

    unsigned short* pool = (unsigned short*)smem;
    const int ybase = 4 * pr - 1;

    #pragma unroll
    for (int p = 0; p < 2; p++) {       // co half (fully unrolled: rule #20)
        #pragma unroll
        for (int tt = 0; tt < 5; tt++) {
            int t5 = w * 5 + tt;
            int r  = t5 >> 4;
            int x  = ((t5 & 15) << 4) + (lane & 15);
            bool dead = (ybase + r) < 0;      // y=-1 pad row -> -inf
            #pragma unroll
            for (int m2 = 0; m2 < 2; m2++) {
                int mt  = p * 2 + m2;
                int col = m2 * 16 + ((lane >> 4) << 2);   // co & 31 (4-aligned)
                unsigned long long pk = 0;
                #pragma unroll
                for (int q = 0; q < 4; q++) {
                    float v = dead ? -INFINITY : fast_mish(acc[tt][mt][q]);
                    pk |= (unsigned long long)f2bf(v) << (16 * q);
                }
                int byte = (((r * 256 + x) * 32) + col) * 2;
                byte ^= (x & 7) << 4;
                *reinterpret_cast<unsigned long long*>((char*)pool + byte) = pk;
            }
        }
        __syncthreads();
        for (int i = tid; i < 8192; i += 1024) {
            int pp = i >> 12;            // pooled row 2pr+pp
            int c  = (i >> 5) & 127;     // pooled col
            int cl = i & 31;
            float m = -INFINITY;
            #pragma unroll
            for (int dy = 0; dy < 3; dy++) {
                int lr = 2 * pp + dy;
                #pragma unroll
                for (int dx = 0; dx < 3; dx++) {
                    int x = 2 * c - 1 + dx;
                    if (x < 0) continue;                  // x<=255 always
                    int byte = ((((lr * 256) + x) * 32) + cl) * 2;
                    byte ^= (x & 7) << 4;
                    unsigned short hv = *reinterpret_cast<const unsigned short*>((char*)pool + byte);
                    m = fmaxf(m, __uint_as_float((unsigned)hv << 16));
                }
            }
            unsigned short* dst = (unsigned short*)(feat1 + (size_t)n * F1_IMG_STRIDE
                + (size_t)(2 * pr + pp + 4) * F1_ROW_STRIDE + (size_t)(c + 4) * 64 + p * 32 + cl);
            *dst = f2bf(m);
        }
        __syncthreads();
    }
}

// ------------- kernel 3: conv2 via MFMA + mish -> pre2 chunk (channel-last, NO pooling) -------
// Processes 32 images starting at n0. block = (nl, ch2, rq): rows y = 4rq..4rq+3 x 128 cols
// x 32 co. R11's proven staging/MFMA core; epilogue = plain global stores.
// LDS = 36KB weights only -> 3-4 blocks/CU for latency hiding.
__global__ __launch_bounds__(512, 4) void conv2_mfma_kernel(
    const __hip_bfloat16* __restrict__ feat1,
    const unsigned short* __restrict__ w2bf,   // [tap][co][ci] bf16
    __hip_bfloat16* __restrict__ pre2,         // [32][128][128][64] (chunk-local)
    int n0)
{
    // XCD-chunked swizzle: 2048 blocks -> 8 XCDs x 256
    int b2 = ((blockIdx.x & 7) << 8) + (blockIdx.x >> 3);
    const int nl  = b2 >> 6;          // chunk-local image 0..31
    const int ch2 = (b2 >> 5) & 1;    // co half: co = ch2*32 + [0,32)
    const int rq  = b2 & 31;          // row quad
    const int n   = n0 + nl;          // global image
    const int tid  = threadIdx.x;
    const int lane = tid & 63;
    const int w    = tid >> 6;        // 0..7
    const int lrow = w >> 1;          // local row 0..3
    const int chalf = w & 1;          // col half
    const int y = 4 * rq + lrow;      // pre-pool row 0..127

    __shared__ __align__(16) char smem[36864];   // weights [9][32co][64ci] bf16, XOR-swizzled

    // ---- stage this co-half's weights (R11 verbatim) ----
    for (int i = tid; i < 18432; i += 512) {      // 9*32*64
        int t    = i >> 11;
        int co32 = (i >> 6) & 31;
        int ci   = i & 63;
        int byte = (((((t << 5) + co32) << 6) + ci) << 1) ^ ((co32 & 7) << 4);
        *reinterpret_cast<unsigned short*>(smem + byte) =
            w2bf[((t << 6) + ch2 * 32 + co32) * 64 + ci];
    }
    __syncthreads();

    f32x4 acc[2][4];
    #pragma unroll
    for (int mt = 0; mt < 2; mt++)
        #pragma unroll
        for (int nt = 0; nt < 4; nt++)
            acc[mt][nt] = (f32x4){0.f, 0.f, 0.f, 0.f};

    // B lane base: feat1 row (y-2)+4 = y+2, col (lane&15) + chalf*64 + (-2) + 4
    const __hip_bfloat16* bbase = feat1 + (size_t)n * F1_IMG_STRIDE
        + ((size_t)(y + 2) * F1_C + (lane & 15) + chalf * 64 + 2) * 64
        + ((lane >> 4) << 3);

    #pragma unroll
    for (int ky = 0; ky < 3; ky++) {
        #pragma unroll
        for (int kx = 0; kx < 3; kx++) {
            const int t = ky * 3 + kx;
            #pragma unroll
            for (int s = 0; s < 2; s++) {
                bf16x8 a[2];
                #pragma unroll
                for (int mt = 0; mt < 2; mt++) {
                    int co32 = mt * 16 + (lane & 15);
                    int abyte = (((((t << 5) + co32) << 6) + (s << 5) + ((lane >> 4) << 3)) << 1)
                                ^ ((co32 & 7) << 4);
                    a[mt] = *reinterpret_cast<const bf16x8*>(smem + abyte);
                }
                const __hip_bfloat16* bp = bbase + (ky * 2 * F1_C + kx * 2) * 64 + s * 32;
                #pragma unroll
                for (int nt = 0; nt < 4; nt++) {
                    bf16x8 b = *reinterpret_cast<const bf16x8*>(bp + nt * 1024);
                    #pragma unroll
                    for (int mt = 0; mt < 2; mt++)
                        acc[mt][nt] = __builtin_amdgcn_mfma_f32_16x16x32_bf16(
                            a[mt], b, acc[mt][nt], 0, 0, 0);
                }
            }
        }
    }

    // ---- epilogue: mish -> packed bf16 global stores (C/D map: row=(lane>>4)*4+r4, col=lane&15)
    #pragma unroll
    for (int nt = 0; nt < 4; nt++) {
        int col = chalf * 64 + nt * 16 + (lane & 15);
        #pragma unroll
        for (int mt = 0; mt < 2; mt++) {
            int co4 = ch2 * 32 + mt * 16 + ((lane >> 4) << 2);   // 4-aligned co
            unsigned long long pk = 0;
            #pragma unroll
            for (int r4 = 0; r4 < 4; r4++)
                pk |= (unsigned long long)f2bf(fast_mish(acc[mt][nt][r4])) << (16 * r4);
            *reinterpret_cast<unsigned long long*>(
                pre2 + (((size_t)(nl * 128 + y) * 128 + col) * 64 + co4)) = pk;
        }
    }
}

// ------------- kernel 4: 3x3 s2 maxpool over pre2 chunk + feature scatter -------------
// block = (nl, ph): 64 pooled cols x 64 co; thread = (pw, co-group of 16).
__global__ __launch_bounds__(256) void pool2_scatter_kernel(
    const __hip_bfloat16* __restrict__ pre2,   // [32][128][128][64] (chunk-local)
    const int*   __restrict__ lin_pt,
    float*       __restrict__ out,
    int n0)
{
    int b2 = ((blockIdx.x & 7) << 8) + (blockIdx.x >> 3);   // 2048 = 8 x 256
    const int nl = b2 >> 6;              // chunk-local image 0..31
    const int ph = b2 & 63;
    const int pw  = threadIdx.x >> 2;    // 0..63
    const int cog = threadIdx.x & 3;     // co base = cog*16

    int lin = lin_pt[((n0 + nl) << 12) + (ph << 6) + pw];
    if (lin < 0) return;                 // invalid point: nothing to pool or scatter

    float m[16];
    #pragma unroll
    for (int k = 0; k < 16; k++) m[k] = -INFINITY;

    #pragma unroll
    for (int dy = 0; dy < 3; dy++) {
        int yy = 2 * ph - 1 + dy;
        if (yy < 0 || yy > 127) continue;
        #pragma unroll
        for (int dx = 0; dx < 3; dx++) {
            int xx = 2 * pw - 1 + dx;
            if (xx < 0 || xx > 127) continue;
            const unsigned short* p = (const unsigned short*)(pre2
                + ((size_t)(nl * 128 + yy) * 128 + xx) * 64 + cog * 16);
            #pragma unroll
            for (int h = 0; h < 2; h++) {
                bf16x8 v = *reinterpret_cast<const bf16x8*>(p + h * 8);
                #pragma unroll
                for (int j = 0; j < 8; j++)
                    m[h * 8 + j] = fmaxf(m[h * 8 + j],
                        __uint_as_float((unsigned)(unsigned short)v[j] << 16));
            }
        }
    }

    float* base = out + (size_t)(lin >> 15) * 2097152 + (lin & 32767);
    #pragma unroll
    for (int k = 0; k < 16; k++)
        atomicAdd(base + (size_t)(cog * 16 + k) * 32768, m[k]);
}

// ---------------- launcher ----------------
extern "C" void kernel_launch(void* const* d_in, const int* in_sizes, int n_in,
                              void* d_out, int out_size, void* d_ws, size_t ws_size,
                              hipStream_t stream)
{
    const float* rgb   = (const float*)d_in[0];
    const float* sxyz  = (const float*)d_in[1];
    const float* w1    = (const float*)d_in[2];
    const float* w2    = (const float*)d_in[3];
    const int*   index = (const int*)d_in[4];
    float* out = (float*)d_out;

    __hip_bfloat16* feat1 = (__hip_bfloat16*)d_ws;
    int* lin_pt = (int*)((char*)d_ws + FEAT1_BYTES);
    unsigned short* w2bf = (unsigned short*)((char*)d_ws + FEAT1_BYTES + LINPT_BYTES);
    __hip_bfloat16* pre2 = (__hip_bfloat16*)((char*)d_ws + FEAT1_BYTES + LINPT_BYTES + W2BF_BYTES);

    hipMemsetAsync(d_out, 0, (size_t)out_size * 4, stream);
    hipMemsetAsync(d_ws, 0, FEAT1_BYTES, stream);   // zeroes feat1 padding too

    w2cvt_kernel<<<144, 256, 0, stream>>>(w2, w2bf);
    point_kernel<<<1024, 256, 0, stream>>>(rgb, sxyz, index, out, lin_pt);
    conv1_mfma_kernel<<<4096, 1024, 0, stream>>>(rgb, w1, feat1);
    // two chunks of 32 images; stream order serializes conv2(c) -> pool(c) -> conv2(c+1)
    for (int c = 0; c < 2; c++) {
        conv2_mfma_kernel<<<2048, 512, 0, stream>>>(feat1, w2bf, pre2, c * 32);
        pool2_scatter_kernel<<<2048, 256, 0, stream>>>(pre2, lin_pt, out, c * 32);
    }
}

// Round 15
// 1254.778 us; speedup vs baseline: 1.0867x; 1.0867x over previous
//
#include <hip/hip_runtime.h>
#include <hip/hip_bf16.h>
#include <math.h>

// ---------------- problem constants ----------------
#define N_IMG 64
#define CH    64      // PCN_H
#define F1_R  136     // feat1 padded rows: row y stored at y+4  (used 1..133)
#define F1_C  136     // feat1 padded cols: col x stored at x+4  (used 2..133)
// feat1 channel-last: [n][F1_R][F1_C][64] bf16
#define F1_IMG_STRIDE ((size_t)F1_R * F1_C * 64)
#define F1_ROW_STRIDE (F1_C * 64)
#define FEAT1_BYTES ((size_t)N_IMG * F1_IMG_STRIDE * 2)
#define LINPT_BYTES (262144 * 4)
#define W2BF_BYTES (36864 * 2)
// pre2 (CHUNKED): conv2 pre-pool output for 32 images, [32][128][128][64] bf16 = 67108864 B
// d_ws usage: 151519232 + 1048576 + 73728 + 67108864 = 219750400 B (< 256 MiB)

// d_out layout (floats):
//   feature_map (8,64,8,64,64)  : [0, 16777216)
//   counts      (8,1,8,64,64)   : [16777216, 17039360)
//   rgb_map     (8,3,8,64,64)   : [17039360, 17825792)
#define OUT_CNT_BASE 16777216
#define OUT_RGB_BASE 17039360

typedef short bf16x8 __attribute__((ext_vector_type(8)));
typedef float f32x4  __attribute__((ext_vector_type(4)));

// mish(x) = x * tanh(softplus(x)) = x * (t^2+2t)/(t^2+2t+2), t=e^x
// clamp-free: for x>30 the ratio saturates to 1 -> y = x (exact to f32). |x|<=15 for this data.
__device__ __forceinline__ float fast_mish(float x) {
    float t = __expf(fminf(x, 30.0f));
    float n = t * (t + 2.0f);
    return x * (n / (n + 2.0f));
}

// float -> bf16 bits, round-to-nearest-even (handles +-inf correctly)
__device__ __forceinline__ unsigned short f2bf(float f) {
    unsigned u = __float_as_uint(f);
    unsigned r = (u + 0x7FFFu + ((u >> 16) & 1u)) >> 16;
    return (unsigned short)r;
}

__device__ __forceinline__ float bf2f(unsigned short h) {
    return __uint_as_float((unsigned)h << 16);
}

// ------------- kernel 0: w2 -> bf16 [tap][co][ci] (once, global) -------------
__global__ __launch_bounds__(256) void w2cvt_kernel(
    const float* __restrict__ w2, unsigned short* __restrict__ w2bf)
{
    int i = blockIdx.x * 256 + threadIdx.x;    // 36864 = 9*64*64
    if (i < 36864) {
        int t  = i >> 12;
        int co = (i >> 6) & 63;
        int ci = i & 63;
        w2bf[i] = f2bf(w2[(co * 64 + ci) * 9 + t]);
    }
}

// ------------- kernel 1: per-point binning + rgb/count scatter -------------
__global__ __launch_bounds__(256) void point_kernel(
    const float* __restrict__ rgb,
    const float* __restrict__ sxyz,
    const int*   __restrict__ index,
    float*       __restrict__ out,
    int*         __restrict__ lin_pt)
{
    int p = blockIdx.x * 256 + threadIdx.x;      // 64*64*64 = 262144 points
    int n  = p >> 12;
    int r  = p & 4095;
    int hs = r >> 6;
    int ws = r & 63;

    int row = hs * 4 + 2, col = ws * 4 + 2;
    const float* sx = sxyz + (size_t)n * 3 * 65536;
    float X = sx[row * 256 + col];
    float Y = sx[65536 + row * 256 + col];
    float Z = sx[2 * 65536 + row * 256 + col];

    // replicate JAX op order + trunc-toward-zero int cast
    int hb = (int)(((X + 5.0f) * 64.0f) / 10.0f);
    int wb = (int)(((Y + 5.0f) * 64.0f) / 10.0f);
    int vb = (int)((Z * 8.0f) / 3.0f);
    bool valid = (hb >= 0) & (hb < 64) & (wb >= 0) & (wb < 64) & (vb >= 0) & (vb < 8);

    int b   = index[n];
    int lin = ((b * 8 + vb) * 64 + hb) * 64 + wb;
    lin_pt[p] = valid ? lin : -1;

    if (valid) {
        atomicAdd(out + OUT_CNT_BASE + lin, 1.0f);
        int rem = lin & 32767;
        #pragma unroll
        for (int c = 0; c < 3; c++) {
            const float* rg = rgb + (size_t)(n * 3 + c) * 65536;
            float s = 0.0f;
            #pragma unroll
            for (int i = 0; i < 4; i++)
                #pragma unroll
                for (int j = 0; j < 4; j++)
                    s += rg[(hs * 4 + i) * 256 + (ws * 4 + j)];
            atomicAdd(out + OUT_RGB_BASE + b * 98304 + c * 32768 + rem, s * 0.0625f);
        }
    }
}

// ------------- kernel 2: conv1 via MFMA + mish + maxpool3s2 -> feat1 (channel-last) ----------
__global__ __launch_bounds__(1024) void conv1_mfma_kernel(
    const float* __restrict__ rgb,
    const float* __restrict__ w1,
    __hip_bfloat16* __restrict__ feat1)
{
    int b2 = ((blockIdx.x & 7) << 9) + (blockIdx.x >> 3);   // XCD-chunked swizzle (4096 = 8x512)
    const int n  = b2 >> 6;
    const int pr = b2 & 63;
    const int tid  = threadIdx.x;
    const int lane = tid & 63;
    const int w    = tid >> 6;       // 0..15

    __shared__ __align__(16) char smem[81920];
    unsigned short* wlds = (unsigned short*)smem;
    unsigned short* in_t = (unsigned short*)(smem + 4096);

    // ---- stage weights [co][k], k = ci*9 + ky*3 + kx (k>=27 -> 0)
    for (int i = tid; i < 2048; i += 1024) {
        int co = i >> 5, k = i & 31;
        wlds[i] = (k < 27) ? f2bf(w1[co * 27 + k]) : (unsigned short)0;
    }
    // ---- stage input tile: rows 4pr-3..4pr+5, cols -2..261, bf16; tail 16 zeros
    {
        const float* img = rgb + (size_t)n * 3 * 65536;
        for (int i = tid; i < 7144; i += 1024) {
            unsigned short v = 0;
            if (i < 7128) {
                int ci  = i / 2376;
                int rem = i - ci * 2376;
                int rr  = rem / 264;
                int cc  = rem - rr * 264;
                int gy  = 4 * pr - 3 + rr;
                int gx  = cc - 2;
                if (gy >= 0 && gy < 256 && gx >= 0 && gx < 256)
                    v = f2bf(img[ci * 65536 + gy * 256 + gx]);
            }
            in_t[i] = v;
        }
    }
    __syncthreads();

    // ---- per-lane B gather offsets (bytes) for k = (lane>>4)*8 + j
    int boff[8];
    #pragma unroll
    for (int j = 0; j < 8; j++) {
        int k = ((lane >> 4) << 3) + j;
        if (k < 27) {
            int ci = k / 9, t = k - 9 * ci, ky = t / 3, kx = t - 3 * ky;
            boff[j] = (ci * 2376 + 2 * ky * 264 + 2 * kx + (lane & 15)) * 2;
        } else {
            boff[j] = 7128 * 2;     // zero slot
        }
    }

    // ---- A fragments (weights), k-map identical to B
    bf16x8 a[4];
    #pragma unroll
    for (int mt = 0; mt < 4; mt++)
        a[mt] = *reinterpret_cast<const bf16x8*>(
            wlds + (mt * 16 + (lane & 15)) * 32 + ((lane >> 4) << 3));

    f32x4 acc[5][4];
    #pragma unroll
    for (int tt = 0; tt < 5; tt++)
        #pragma unroll
        for (int mt = 0; mt < 4; mt++)
            acc[tt][mt] = (f32x4){0.f, 0.f, 0.f, 0.f};

    const char* in_b = (const char*)in_t;
    #pragma unroll
    for (int tt = 0; tt < 5; tt++) {
        int t5 = w * 5 + tt;             // 0..79: 5 rows x 16 col-tiles
        int r  = t5 >> 4;
        int x0 = (t5 & 15) << 4;
        int base = (r * 264 + x0) * 2;
        unsigned short e[8];
        #pragma unroll
        for (int j = 0; j < 8; j++)
            e[j] = *reinterpret_cast<const unsigned short*>(in_b + base + boff[j]);
        bf16x8 b;
        #pragma unroll
        for (int j = 0; j < 8; j++) b[j] = (short)e[j];
        #pragma unroll
        for (int mt = 0; mt < 4; mt++)
            acc[tt][mt] = __builtin_amdgcn_mfma_f32_16x16x32_bf16(a[mt], b, acc[tt][mt], 0, 0, 0);
    }

    __syncthreads();   // wlds/in_t dead; reuse LDS as pool tile

    unsigned short* pool = (unsigned short*)smem;
    const int ybase = 4 * pr - 1;

    // pool-read task (one per thread per pass): (pp, c, co-group-of-8)
    const int r_pp  = tid >> 9;           // pooled row sel 0/1
    const int r_c   = (tid >> 2) & 127;   // pooled col
    const int r_cl0 = (tid & 3) * 8;      // co-group base within half

    #pragma unroll
    for (int p = 0; p < 2; p++) {       // co half (fully unrolled: rule #20)
        // ---- write phase (R14 verbatim): mish -> u64 packs into swizzled pool tile ----
        #pragma unroll
        for (int tt = 0; tt < 5; tt++) {
            int t5 = w * 5 + tt;
            int r  = t5 >> 4;
            int x  = ((t5 & 15) << 4) + (lane & 15);
            bool dead = (ybase + r) < 0;      // y=-1 pad row -> -inf
            #pragma unroll
            for (int m2 = 0; m2 < 2; m2++) {
                int mt  = p * 2 + m2;
                int col = m2 * 16 + ((lane >> 4) << 2);   // co & 31 (4-aligned)
                unsigned long long pk = 0;
                #pragma unroll
                for (int q = 0; q < 4; q++) {
                    float v = dead ? -INFINITY : fast_mish(acc[tt][mt][q]);
                    pk |= (unsigned long long)f2bf(v) << (16 * q);
                }
                int byte = (((r * 256 + x) * 32) + col) * 2;
                byte ^= (x & 7) << 4;
                *reinterpret_cast<unsigned long long*>((char*)pool + byte) = pk;
            }
        }
        __syncthreads();
        // ---- read phase (vectorized): 9 x ds_read_b128 per thread, 8 co at once ----
        {
            float m[8];
            #pragma unroll
            for (int j = 0; j < 8; j++) m[j] = -INFINITY;
            #pragma unroll
            for (int dy = 0; dy < 3; dy++) {
                int lr = 2 * r_pp + dy;               // 0..4, always in tile
                #pragma unroll
                for (int dx = 0; dx < 3; dx++) {
                    int x = 2 * r_c - 1 + dx;         // -1..255
                    if (x < 0) continue;
                    int byte = ((((lr * 256) + x) * 32) + r_cl0) * 2;
                    byte ^= (x & 7) << 4;
                    bf16x8 v = *reinterpret_cast<const bf16x8*>((char*)pool + byte);
                    #pragma unroll
                    for (int j = 0; j < 8; j++)
                        m[j] = fmaxf(m[j], bf2f((unsigned short)v[j]));
                }
            }
            bf16x8 vpk;
            #pragma unroll
            for (int j = 0; j < 8; j++) vpk[j] = (short)f2bf(m[j]);
            *reinterpret_cast<bf16x8*>((unsigned short*)(feat1
                + (size_t)n * F1_IMG_STRIDE
                + (size_t)(2 * pr + r_pp + 4) * F1_ROW_STRIDE
                + (size_t)(r_c + 4) * 64 + p * 32 + r_cl0)) = vpk;
        }
        __syncthreads();
    }
}

// ------------- kernel 3: conv2 via MFMA + mish -> pre2 chunk (channel-last, NO pooling) -------
// Processes 32 images starting at n0. block = (nl, ch2, rq): rows y = 4rq..4rq+3 x 128 cols
// x 32 co. R11's proven staging/MFMA core; epilogue = plain global stores.
__global__ __launch_bounds__(512, 4) void conv2_mfma_kernel(
    const __hip_bfloat16* __restrict__ feat1,
    const unsigned short* __restrict__ w2bf,   // [tap][co][ci] bf16
    __hip_bfloat16* __restrict__ pre2,         // [32][128][128][64] (chunk-local)
    int n0)
{
    // XCD-chunked swizzle: 2048 blocks -> 8 XCDs x 256
    int b2 = ((blockIdx.x & 7) << 8) + (blockIdx.x >> 3);
    const int nl  = b2 >> 6;          // chunk-local image 0..31
    const int ch2 = (b2 >> 5) & 1;    // co half: co = ch2*32 + [0,32)
    const int rq  = b2 & 31;          // row quad
    const int n   = n0 + nl;          // global image
    const int tid  = threadIdx.x;
    const int lane = tid & 63;
    const int w    = tid >> 6;        // 0..7
    const int lrow = w >> 1;          // local row 0..3
    const int chalf = w & 1;          // col half
    const int y = 4 * rq + lrow;      // pre-pool row 0..127

    __shared__ __align__(16) char smem[36864];   // weights [9][32co][64ci] bf16, XOR-swizzled

    // ---- stage this co-half's weights, u32-vectorized ----
    {
        const unsigned* src = (const unsigned*)w2bf;   // ci pairs
        for (int i2 = tid; i2 < 9216; i2 += 512) {     // 9*32*32
            int t    = i2 >> 10;
            int rem  = i2 & 1023;
            int co32 = rem >> 5;
            int ci2  = rem & 31;
            int byte = (((((t << 5) + co32) << 6) + (ci2 << 1)) << 1) ^ ((co32 & 7) << 4);
            *reinterpret_cast<unsigned*>(smem + byte) =
                src[((t << 6) + ch2 * 32 + co32) * 32 + ci2];
        }
    }
    __syncthreads();

    f32x4 acc[2][4];
    #pragma unroll
    for (int mt = 0; mt < 2; mt++)
        #pragma unroll
        for (int nt = 0; nt < 4; nt++)
            acc[mt][nt] = (f32x4){0.f, 0.f, 0.f, 0.f};

    // B lane base: feat1 row (y-2)+4 = y+2, col (lane&15) + chalf*64 + (-2) + 4
    const __hip_bfloat16* bbase = feat1 + (size_t)n * F1_IMG_STRIDE
        + ((size_t)(y + 2) * F1_C + (lane & 15) + chalf * 64 + 2) * 64
        + ((lane >> 4) << 3);

    #pragma unroll
    for (int ky = 0; ky < 3; ky++) {
        #pragma unroll
        for (int kx = 0; kx < 3; kx++) {
            const int t = ky * 3 + kx;
            #pragma unroll
            for (int s = 0; s < 2; s++) {
                bf16x8 a[2];
                #pragma unroll
                for (int mt = 0; mt < 2; mt++) {
                    int co32 = mt * 16 + (lane & 15);
                    int abyte = (((((t << 5) + co32) << 6) + (s << 5) + ((lane >> 4) << 3)) << 1)
                                ^ ((co32 & 7) << 4);
                    a[mt] = *reinterpret_cast<const bf16x8*>(smem + abyte);
                }
                const __hip_bfloat16* bp = bbase + (ky * 2 * F1_C + kx * 2) * 64 + s * 32;
                #pragma unroll
                for (int nt = 0; nt < 4; nt++) {
                    bf16x8 b = *reinterpret_cast<const bf16x8*>(bp + nt * 1024);
                    #pragma unroll
                    for (int mt = 0; mt < 2; mt++)
                        acc[mt][nt] = __builtin_amdgcn_mfma_f32_16x16x32_bf16(
                            a[mt], b, acc[mt][nt], 0, 0, 0);
                }
            }
        }
    }

    // ---- epilogue: mish -> packed bf16 global stores (C/D map: row=(lane>>4)*4+r4, col=lane&15)
    #pragma unroll
    for (int nt = 0; nt < 4; nt++) {
        int col = chalf * 64 + nt * 16 + (lane & 15);
        #pragma unroll
        for (int mt = 0; mt < 2; mt++) {
            int co4 = ch2 * 32 + mt * 16 + ((lane >> 4) << 2);   // 4-aligned co
            unsigned long long pk = 0;
            #pragma unroll
            for (int r4 = 0; r4 < 4; r4++)
                pk |= (unsigned long long)f2bf(fast_mish(acc[mt][nt][r4])) << (16 * r4);
            *reinterpret_cast<unsigned long long*>(
                pre2 + (((size_t)(nl * 128 + y) * 128 + col) * 64 + co4)) = pk;
        }
    }
}

// ------------- kernel 4: 3x3 s2 maxpool over pre2 chunk + feature scatter -------------
// block = (nl, ph): 64 pooled cols x 64 co; thread = (pw, co-group of 16).
__global__ __launch_bounds__(256) void pool2_scatter_kernel(
    const __hip_bfloat16* __restrict__ pre2,   // [32][128][128][64] (chunk-local)
    const int*   __restrict__ lin_pt,
    float*       __restrict__ out,
    int n0)
{
    int b2 = ((blockIdx.x & 7) << 8) + (blockIdx.x >> 3);   // 2048 = 8 x 256
    const int nl = b2 >> 6;              // chunk-local image 0..31
    const int ph = b2 & 63;
    const int pw  = threadIdx.x >> 2;    // 0..63
    const int cog = threadIdx.x & 3;     // co base = cog*16

    int lin = lin_pt[((n0 + nl) << 12) + (ph << 6) + pw];
    if (lin < 0) return;                 // invalid point: nothing to pool or scatter

    float m[16];
    #pragma unroll
    for (int k = 0; k < 16; k++) m[k] = -INFINITY;

    #pragma unroll
    for (int dy = 0; dy < 3; dy++) {
        int yy = 2 * ph - 1 + dy;
        if (yy < 0 || yy > 127) continue;
        #pragma unroll
        for (int dx = 0; dx < 3; dx++) {
            int xx = 2 * pw - 1 + dx;
            if (xx < 0 || xx > 127) continue;
            const unsigned short* p = (const unsigned short*)(pre2
                + ((size_t)(nl * 128 + yy) * 128 + xx) * 64 + cog * 16);
            #pragma unroll
            for (int h = 0; h < 2; h++) {
                bf16x8 v = *reinterpret_cast<const bf16x8*>(p + h * 8);
                #pragma unroll
                for (int j = 0; j < 8; j++)
                    m[h * 8 + j] = fmaxf(m[h * 8 + j], bf2f((unsigned short)v[j]));
            }
        }
    }

    float* base = out + (size_t)(lin >> 15) * 2097152 + (lin & 32767);
    #pragma unroll
    for (int k = 0; k < 16; k++)
        atomicAdd(base + (size_t)(cog * 16 + k) * 32768, m[k]);
}

// ---------------- launcher ----------------
extern "C" void kernel_launch(void* const* d_in, const int* in_sizes, int n_in,
                              void* d_out, int out_size, void* d_ws, size_t ws_size,
                              hipStream_t stream)
{
    const float* rgb   = (const float*)d_in[0];
    const float* sxyz  = (const float*)d_in[1];
    const float* w1    = (const float*)d_in[2];
    const float* w2    = (const float*)d_in[3];
    const int*   index = (const int*)d_in[4];
    float* out = (float*)d_out;

    __hip_bfloat16* feat1 = (__hip_bfloat16*)d_ws;
    int* lin_pt = (int*)((char*)d_ws + FEAT1_BYTES);
    unsigned short* w2bf = (unsigned short*)((char*)d_ws + FEAT1_BYTES + LINPT_BYTES);
    __hip_bfloat16* pre2 = (__hip_bfloat16*)((char*)d_ws + FEAT1_BYTES + LINPT_BYTES + W2BF_BYTES);

    hipMemsetAsync(d_out, 0, (size_t)out_size * 4, stream);
    hipMemsetAsync(d_ws, 0, FEAT1_BYTES, stream);   // zeroes feat1 padding too

    w2cvt_kernel<<<144, 256, 0, stream>>>(w2, w2bf);
    point_kernel<<<1024, 256, 0, stream>>>(rgb, sxyz, index, out, lin_pt);
    conv1_mfma_kernel<<<4096, 1024, 0, stream>>>(rgb, w1, feat1);
    // two chunks of 32 images; stream order serializes conv2(c) -> pool(c) -> conv2(c+1)
    for (int c = 0; c < 2; c++) {
        conv2_mfma_kernel<<<2048, 512, 0, stream>>>(feat1, w2bf, pre2, c * 32);
        pool2_scatter_kernel<<<2048, 256, 0, stream>>>(pre2, lin_pt, out, c * 32);
    }
}

// Round 16
// 1220.346 us; speedup vs baseline: 1.1173x; 1.0282x over previous
//
#include <hip/hip_runtime.h>
#include <hip/hip_bf16.h>
#include <math.h>

// ---------------- problem constants ----------------
#define N_IMG 64
#define CH    64      // PCN_H
#define F1_R  136     // feat1 padded rows: row y stored at y+4  (used 1..133)
#define F1_C  136     // feat1 padded cols: col x stored at x+4  (used 2..133)
// feat1 channel-last: [n][F1_R][F1_C][64] bf16
#define F1_IMG_STRIDE ((size_t)F1_R * F1_C * 64)
#define F1_ROW_STRIDE (F1_C * 64)
#define FEAT1_BYTES ((size_t)N_IMG * F1_IMG_STRIDE * 2)
#define LINPT_BYTES (262144 * 4)
#define W2BF_BYTES (36864 * 2)
// pre2 (CHUNKED): conv2 pre-pool output for 32 images, [32][128][128][64] bf16 = 67108864 B
// d_ws usage: 151519232 + 1048576 + 73728 + 67108864 = 219750400 B (< 256 MiB)

// d_out layout (floats):
//   feature_map (8,64,8,64,64)  : [0, 16777216)
//   counts      (8,1,8,64,64)   : [16777216, 17039360)
//   rgb_map     (8,3,8,64,64)   : [17039360, 17825792)
#define OUT_CNT_BASE 16777216
#define OUT_RGB_BASE 17039360

typedef short bf16x8 __attribute__((ext_vector_type(8)));
typedef float f32x4  __attribute__((ext_vector_type(4)));

// mish(x) = x * tanh(softplus(x)) = x * (t^2+2t)/(t^2+2t+2), t=e^x
// clamp-free: for x>30 the ratio saturates to 1 -> y = x (exact to f32). |x|<=15 for this data.
__device__ __forceinline__ float fast_mish(float x) {
    float t = __expf(fminf(x, 30.0f));
    float n = t * (t + 2.0f);
    return x * (n / (n + 2.0f));
}

// float -> bf16 bits, round-to-nearest-even (handles +-inf correctly)
__device__ __forceinline__ unsigned short f2bf(float f) {
    unsigned u = __float_as_uint(f);
    unsigned r = (u + 0x7FFFu + ((u >> 16) & 1u)) >> 16;
    return (unsigned short)r;
}

__device__ __forceinline__ float bf2f(unsigned short h) {
    return __uint_as_float((unsigned)h << 16);
}

// ------------- kernel 0: w2 -> bf16 [tap][co][ci] (once, global) -------------
__global__ __launch_bounds__(256) void w2cvt_kernel(
    const float* __restrict__ w2, unsigned short* __restrict__ w2bf)
{
    int i = blockIdx.x * 256 + threadIdx.x;    // 36864 = 9*64*64
    if (i < 36864) {
        int t  = i >> 12;
        int co = (i >> 6) & 63;
        int ci = i & 63;
        w2bf[i] = f2bf(w2[(co * 64 + ci) * 9 + t]);
    }
}

// ------------- kernel 1: per-point binning + rgb/count scatter -------------
__global__ __launch_bounds__(256) void point_kernel(
    const float* __restrict__ rgb,
    const float* __restrict__ sxyz,
    const int*   __restrict__ index,
    float*       __restrict__ out,
    int*         __restrict__ lin_pt)
{
    int p = blockIdx.x * 256 + threadIdx.x;      // 64*64*64 = 262144 points
    int n  = p >> 12;
    int r  = p & 4095;
    int hs = r >> 6;
    int ws = r & 63;

    int row = hs * 4 + 2, col = ws * 4 + 2;
    const float* sx = sxyz + (size_t)n * 3 * 65536;
    float X = sx[row * 256 + col];
    float Y = sx[65536 + row * 256 + col];
    float Z = sx[2 * 65536 + row * 256 + col];

    // replicate JAX op order + trunc-toward-zero int cast
    int hb = (int)(((X + 5.0f) * 64.0f) / 10.0f);
    int wb = (int)(((Y + 5.0f) * 64.0f) / 10.0f);
    int vb = (int)((Z * 8.0f) / 3.0f);
    bool valid = (hb >= 0) & (hb < 64) & (wb >= 0) & (wb < 64) & (vb >= 0) & (vb < 8);

    int b   = index[n];
    int lin = ((b * 8 + vb) * 64 + hb) * 64 + wb;
    lin_pt[p] = valid ? lin : -1;

    if (valid) {
        atomicAdd(out + OUT_CNT_BASE + lin, 1.0f);
        int rem = lin & 32767;
        #pragma unroll
        for (int c = 0; c < 3; c++) {
            const float* rg = rgb + (size_t)(n * 3 + c) * 65536;
            float s = 0.0f;
            #pragma unroll
            for (int i = 0; i < 4; i++)
                #pragma unroll
                for (int j = 0; j < 4; j++)
                    s += rg[(hs * 4 + i) * 256 + (ws * 4 + j)];
            atomicAdd(out + OUT_RGB_BASE + b * 98304 + c * 32768 + rem, s * 0.0625f);
        }
    }
}

// ------------- kernel 2: conv1 via MFMA + mish + maxpool3s2 -> feat1 (channel-last) ----------
// Thread task remap: t5 = row*16 + coltile, so each thread holds all 5 pre-pool rows of
// one column range -> 3-row pool max in REGISTERS post-mish; LDS tile only [2][256][64co].
__global__ __launch_bounds__(1024) void conv1_mfma_kernel(
    const float* __restrict__ rgb,
    const float* __restrict__ w1,
    __hip_bfloat16* __restrict__ feat1)
{
    int b2 = ((blockIdx.x & 7) << 9) + (blockIdx.x >> 3);   // XCD-chunked swizzle (4096 = 8x512)
    const int n  = b2 >> 6;
    const int pr = b2 & 63;
    const int tid  = threadIdx.x;
    const int lane = tid & 63;
    const int w    = tid >> 6;       // 0..15 = column tile

    __shared__ __align__(16) char smem[65536];
    // staging: wlds [64co][32k] @0 (4KB); in_t [3ci][9r][264c]+16 @4096 (14.3KB)
    // epilogue: pool tile [2 pooled rows][256 cols][64 co] bf16 @0 (64KB)
    unsigned short* wlds = (unsigned short*)smem;
    unsigned short* in_t = (unsigned short*)(smem + 4096);

    // ---- stage weights [co][k], k = ci*9 + ky*3 + kx (k>=27 -> 0)
    for (int i = tid; i < 2048; i += 1024) {
        int co = i >> 5, k = i & 31;
        wlds[i] = (k < 27) ? f2bf(w1[co * 27 + k]) : (unsigned short)0;
    }
    // ---- stage input tile: rows 4pr-3..4pr+5, cols -2..261, bf16; tail 16 zeros
    {
        const float* img = rgb + (size_t)n * 3 * 65536;
        for (int i = tid; i < 7144; i += 1024) {
            unsigned short v = 0;
            if (i < 7128) {
                int ci  = i / 2376;
                int rem = i - ci * 2376;
                int rr  = rem / 264;
                int cc  = rem - rr * 264;
                int gy  = 4 * pr - 3 + rr;
                int gx  = cc - 2;
                if (gy >= 0 && gy < 256 && gx >= 0 && gx < 256)
                    v = f2bf(img[ci * 65536 + gy * 256 + gx]);
            }
            in_t[i] = v;
        }
    }
    __syncthreads();

    // ---- per-lane B gather offsets (bytes) for k = (lane>>4)*8 + j
    int boff[8];
    #pragma unroll
    for (int j = 0; j < 8; j++) {
        int k = ((lane >> 4) << 3) + j;
        if (k < 27) {
            int ci = k / 9, t = k - 9 * ci, ky = t / 3, kx = t - 3 * ky;
            boff[j] = (ci * 2376 + 2 * ky * 264 + 2 * kx + (lane & 15)) * 2;
        } else {
            boff[j] = 7128 * 2;     // zero slot
        }
    }

    // ---- A fragments (weights), k-map identical to B
    bf16x8 a[4];
    #pragma unroll
    for (int mt = 0; mt < 4; mt++)
        a[mt] = *reinterpret_cast<const bf16x8*>(
            wlds + (mt * 16 + (lane & 15)) * 32 + ((lane >> 4) << 3));

    f32x4 acc[5][4];   // acc[row r][mt]
    #pragma unroll
    for (int r = 0; r < 5; r++)
        #pragma unroll
        for (int mt = 0; mt < 4; mt++)
            acc[r][mt] = (f32x4){0.f, 0.f, 0.f, 0.f};

    const char* in_b = (const char*)in_t;
    #pragma unroll
    for (int r = 0; r < 5; r++) {        // local pre-pool row; cols fixed = w*16..w*16+15
        int base = (r * 264 + (w << 4)) * 2;
        unsigned short e[8];
        #pragma unroll
        for (int j = 0; j < 8; j++)
            e[j] = *reinterpret_cast<const unsigned short*>(in_b + base + boff[j]);
        bf16x8 b;
        #pragma unroll
        for (int j = 0; j < 8; j++) b[j] = (short)e[j];
        #pragma unroll
        for (int mt = 0; mt < 4; mt++)
            acc[r][mt] = __builtin_amdgcn_mfma_f32_16x16x32_bf16(a[mt], b, acc[r][mt], 0, 0, 0);
    }

    __syncthreads();   // wlds/in_t dead; reuse LDS as pool tile [2][256][64]

    unsigned short* pool = (unsigned short*)smem;
    const int ybase = 4 * pr - 1;
    const int x = (w << 4) + (lane & 15);

    // ---- mish all 5 rows, register row-max -> 2 pooled-row entries, swizzled LDS write ----
    #pragma unroll
    for (int mt = 0; mt < 4; mt++) {
        float mv[5][4];
        #pragma unroll
        for (int r = 0; r < 5; r++) {
            bool dead = (ybase + r) < 0;       // y=-1 pad row -> -inf (only pr=0, r=0)
            #pragma unroll
            for (int q = 0; q < 4; q++)
                mv[r][q] = dead ? -INFINITY : fast_mish(acc[r][mt][q]);
        }
        #pragma unroll
        for (int pp = 0; pp < 2; pp++) {
            int co0 = mt * 16 + ((lane >> 4) << 2);   // 4-aligned co
            unsigned long long pk = 0;
            #pragma unroll
            for (int q = 0; q < 4; q++) {
                float rm = fmaxf(fmaxf(mv[2 * pp][q], mv[2 * pp + 1][q]), mv[2 * pp + 2][q]);
                pk |= (unsigned long long)f2bf(rm) << (16 * q);
            }
            int byte = (((pp * 256 + x) * 64) + co0) * 2;
            byte ^= (x & 7) << 4;
            *reinterpret_cast<unsigned long long*>((char*)pool + byte) = pk;
        }
    }
    __syncthreads();

    // ---- col-max (3 x b128) + store: 2048 tasks = (pp, c, co-group-8), 2 per thread ----
    #pragma unroll
    for (int pp = 0; pp < 2; pp++) {
        int c   = (tid >> 3) & 127;
        int cl0 = (tid & 7) * 8;
        float m[8];
        #pragma unroll
        for (int j = 0; j < 8; j++) m[j] = -INFINITY;
        #pragma unroll
        for (int dx = 0; dx < 3; dx++) {
            int xx = 2 * c - 1 + dx;             // -1..255
            if (xx < 0) continue;
            int byte = ((((pp * 256) + xx) * 64) + cl0) * 2;
            byte ^= (xx & 7) << 4;
            bf16x8 v = *reinterpret_cast<const bf16x8*>((char*)pool + byte);
            #pragma unroll
            for (int j = 0; j < 8; j++)
                m[j] = fmaxf(m[j], bf2f((unsigned short)v[j]));
        }
        bf16x8 vpk;
        #pragma unroll
        for (int j = 0; j < 8; j++) vpk[j] = (short)f2bf(m[j]);
        *reinterpret_cast<bf16x8*>((unsigned short*)(feat1
            + (size_t)n * F1_IMG_STRIDE
            + (size_t)(2 * pr + pp + 4) * F1_ROW_STRIDE
            + (size_t)(c + 4) * 64 + cl0)) = vpk;
    }
}

// ------------- kernel 3: conv2 via MFMA + mish -> pre2 chunk (channel-last, NO pooling) -------
// Processes 32 images starting at n0. block = (nl, ch2, rq): rows y = 4rq..4rq+3 x 128 cols
// x 32 co. R11's proven staging/MFMA core; epilogue = plain global stores.
__global__ __launch_bounds__(512, 4) void conv2_mfma_kernel(
    const __hip_bfloat16* __restrict__ feat1,
    const unsigned short* __restrict__ w2bf,   // [tap][co][ci] bf16
    __hip_bfloat16* __restrict__ pre2,         // [32][128][128][64] (chunk-local)
    int n0)
{
    // XCD-chunked swizzle: 2048 blocks -> 8 XCDs x 256
    int b2 = ((blockIdx.x & 7) << 8) + (blockIdx.x >> 3);
    const int nl  = b2 >> 6;          // chunk-local image 0..31
    const int ch2 = (b2 >> 5) & 1;    // co half: co = ch2*32 + [0,32)
    const int rq  = b2 & 31;          // row quad
    const int n   = n0 + nl;          // global image
    const int tid  = threadIdx.x;
    const int lane = tid & 63;
    const int w    = tid >> 6;        // 0..7
    const int lrow = w >> 1;          // local row 0..3
    const int chalf = w & 1;          // col half
    const int y = 4 * rq + lrow;      // pre-pool row 0..127

    __shared__ __align__(16) char smem[36864];   // weights [9][32co][64ci] bf16, XOR-swizzled

    // ---- stage this co-half's weights, u32-vectorized ----
    {
        const unsigned* src = (const unsigned*)w2bf;   // ci pairs
        for (int i2 = tid; i2 < 9216; i2 += 512) {     // 9*32*32
            int t    = i2 >> 10;
            int rem  = i2 & 1023;
            int co32 = rem >> 5;
            int ci2  = rem & 31;
            int byte = (((((t << 5) + co32) << 6) + (ci2 << 1)) << 1) ^ ((co32 & 7) << 4);
            *reinterpret_cast<unsigned*>(smem + byte) =
                src[((t << 6) + ch2 * 32 + co32) * 32 + ci2];
        }
    }
    __syncthreads();

    f32x4 acc[2][4];
    #pragma unroll
    for (int mt = 0; mt < 2; mt++)
        #pragma unroll
        for (int nt = 0; nt < 4; nt++)
            acc[mt][nt] = (f32x4){0.f, 0.f, 0.f, 0.f};

    // B lane base: feat1 row (y-2)+4 = y+2, col (lane&15) + chalf*64 + (-2) + 4
    const __hip_bfloat16* bbase = feat1 + (size_t)n * F1_IMG_STRIDE
        + ((size_t)(y + 2) * F1_C + (lane & 15) + chalf * 64 + 2) * 64
        + ((lane >> 4) << 3);

    #pragma unroll
    for (int ky = 0; ky < 3; ky++) {
        #pragma unroll
        for (int kx = 0; kx < 3; kx++) {
            const int t = ky * 3 + kx;
            #pragma unroll
            for (int s = 0; s < 2; s++) {
                bf16x8 a[2];
                #pragma unroll
                for (int mt = 0; mt < 2; mt++) {
                    int co32 = mt * 16 + (lane & 15);
                    int abyte = (((((t << 5) + co32) << 6) + (s << 5) + ((lane >> 4) << 3)) << 1)
                                ^ ((co32 & 7) << 4);
                    a[mt] = *reinterpret_cast<const bf16x8*>(smem + abyte);
                }
                const __hip_bfloat16* bp = bbase + (ky * 2 * F1_C + kx * 2) * 64 + s * 32;
                #pragma unroll
                for (int nt = 0; nt < 4; nt++) {
                    bf16x8 b = *reinterpret_cast<const bf16x8*>(bp + nt * 1024);
                    #pragma unroll
                    for (int mt = 0; mt < 2; mt++)
                        acc[mt][nt] = __builtin_amdgcn_mfma_f32_16x16x32_bf16(
                            a[mt], b, acc[mt][nt], 0, 0, 0);
                }
            }
        }
    }

    // ---- epilogue: mish -> packed bf16 global stores (C/D map: row=(lane>>4)*4+r4, col=lane&15)
    #pragma unroll
    for (int nt = 0; nt < 4; nt++) {
        int col = chalf * 64 + nt * 16 + (lane & 15);
        #pragma unroll
        for (int mt = 0; mt < 2; mt++) {
            int co4 = ch2 * 32 + mt * 16 + ((lane >> 4) << 2);   // 4-aligned co
            unsigned long long pk = 0;
            #pragma unroll
            for (int r4 = 0; r4 < 4; r4++)
                pk |= (unsigned long long)f2bf(fast_mish(acc[mt][nt][r4])) << (16 * r4);
            *reinterpret_cast<unsigned long long*>(
                pre2 + (((size_t)(nl * 128 + y) * 128 + col) * 64 + co4)) = pk;
        }
    }
}

// ------------- kernel 4: 3x3 s2 maxpool over pre2 chunk + feature scatter -------------
// block = (nl, ph): 64 pooled cols x 64 co; thread = (pw, co-group of 16).
__global__ __launch_bounds__(256) void pool2_scatter_kernel(
    const __hip_bfloat16* __restrict__ pre2,   // [32][128][128][64] (chunk-local)
    const int*   __restrict__ lin_pt,
    float*       __restrict__ out,
    int n0)
{
    int b2 = ((blockIdx.x & 7) << 8) + (blockIdx.x >> 3);   // 2048 = 8 x 256
    const int nl = b2 >> 6;              // chunk-local image 0..31
    const int ph = b2 & 63;
    const int pw  = threadIdx.x >> 2;    // 0..63
    const int cog = threadIdx.x & 3;     // co base = cog*16

    int lin = lin_pt[((n0 + nl) << 12) + (ph << 6) + pw];
    if (lin < 0) return;                 // invalid point: nothing to pool or scatter

    float m[16];
    #pragma unroll
    for (int k = 0; k < 16; k++) m[k] = -INFINITY;

    #pragma unroll
    for (int dy = 0; dy < 3; dy++) {
        int yy = 2 * ph - 1 + dy;
        if (yy < 0 || yy > 127) continue;
        #pragma unroll
        for (int dx = 0; dx < 3; dx++) {
            int xx = 2 * pw - 1 + dx;
            if (xx < 0 || xx > 127) continue;
            const unsigned short* p = (const unsigned short*)(pre2
                + ((size_t)(nl * 128 + yy) * 128 + xx) * 64 + cog * 16);
            #pragma unroll
            for (int h = 0; h < 2; h++) {
                bf16x8 v = *reinterpret_cast<const bf16x8*>(p + h * 8);
                #pragma unroll
                for (int j = 0; j < 8; j++)
                    m[h * 8 + j] = fmaxf(m[h * 8 + j], bf2f((unsigned short)v[j]));
            }
        }
    }

    float* base = out + (size_t)(lin >> 15) * 2097152 + (lin & 32767);
    #pragma unroll
    for (int k = 0; k < 16; k++)
        atomicAdd(base + (size_t)(cog * 16 + k) * 32768, m[k]);
}

// ---------------- launcher ----------------
extern "C" void kernel_launch(void* const* d_in, const int* in_sizes, int n_in,
                              void* d_out, int out_size, void* d_ws, size_t ws_size,
                              hipStream_t stream)
{
    const float* rgb   = (const float*)d_in[0];
    const float* sxyz  = (const float*)d_in[1];
    const float* w1    = (const float*)d_in[2];
    const float* w2    = (const float*)d_in[3];
    const int*   index = (const int*)d_in[4];
    float* out = (float*)d_out;

    __hip_bfloat16* feat1 = (__hip_bfloat16*)d_ws;
    int* lin_pt = (int*)((char*)d_ws + FEAT1_BYTES);
    unsigned short* w2bf = (unsigned short*)((char*)d_ws + FEAT1_BYTES + LINPT_BYTES);
    __hip_bfloat16* pre2 = (__hip_bfloat16*)((char*)d_ws + FEAT1_BYTES + LINPT_BYTES + W2BF_BYTES);

    hipMemsetAsync(d_out, 0, (size_t)out_size * 4, stream);
    hipMemsetAsync(d_ws, 0, FEAT1_BYTES, stream);   // zeroes feat1 padding too

    w2cvt_kernel<<<144, 256, 0, stream>>>(w2, w2bf);
    point_kernel<<<1024, 256, 0, stream>>>(rgb, sxyz, index, out, lin_pt);
    conv1_mfma_kernel<<<4096, 1024, 0, stream>>>(rgb, w1, feat1);
    // two chunks of 32 images; stream order serializes conv2(c) -> pool(c) -> conv2(c+1)
    for (int c = 0; c < 2; c++) {
        conv2_mfma_kernel<<<2048, 512, 0, stream>>>(feat1, w2bf, pre2, c * 32);
        pool2_scatter_kernel<<<2048, 256, 0, stream>>>(pre2, lin_pt, out, c * 32);
    }
}